// Round 7
// baseline (2555.632 us; speedup 1.0000x reference)
//
#include <hip/hip_runtime.h>
#include <math.h>

// Problem constants (fixed by the reference setup_inputs).
constexpr int N_NODES = 50000;
constexpr int IN_F    = 512;
constexpr int H_F     = 256;
constexpr int OUT_F   = 512;
constexpr int N_EDGE  = 800000;
constexpr int NDIM    = 4;
constexpr long NH     = (long)N_NODES * H_F;   // 12,800,000

#define LEAKY_SLOPE 0.01f

__device__ __forceinline__ float leaky_f(float v) { return v > 0.0f ? v : LEAKY_SLOPE * v; }

typedef __bf16 bf16x8 __attribute__((ext_vector_type(8)));
typedef float  f32x4  __attribute__((ext_vector_type(4)));

// Bijective XCD-aware block remap (proven r3/r5/r6): col-fastest work ids land
// contiguously on one XCD so col-blocks sharing an A row-panel share its L2.
__device__ __forceinline__ void swz_block(int& mb, int& nb) {
  const int nwg = (int)(gridDim.x * gridDim.y);
  const int hw  = (int)(blockIdx.y * gridDim.x + blockIdx.x);
  const int xcd = hw & 7, idx = hw >> 3;
  const int q8 = nwg >> 3, r8 = nwg & 7;
  const int wk = (xcd < r8 ? xcd * (q8 + 1) : r8 * (q8 + 1) + (xcd - r8) * q8) + idx;
  nb = wk % (int)gridDim.x;
  mb = wk / (int)gridDim.x;
}

// ---------------------------------------------------------------------------
// Split-bf16 MFMA GEMM — 256x128 tile, 512 threads (8 waves = 4m x 2n, each
// wave the r6-proven 64x64 = 4x4 frag set). Same r6 schedule:
//   per K-step: readFrags -> issue global loads(kt+1) -> MFMA
//               -> __syncthreads -> ds_write(kt+1) -> __syncthreads
// Rationale: cross-round calibration shows time ~ 2.1us per CU-block-K-step
// regardless of staging scheme; 256-row tiles cut G3 steps 4x, G2 8x.
// LDS: A 256x32 hi/lo + B 128x32 hi/lo = 48KB, linear + chunk-XOR map
// (SQ_LDS_BANK_CONFLICT = 0, r3/r6-verified). __syncthreads only (both
// container failures had raw s_waitcnt asm; never again).
//   AF32=true : A fp32 (x / proj), float4 loads + VALU hi/lo split.
//   AF32=false: A pre-split bf16 hi/lo, int4 copies, no cvt.
// 3 MFMA per product (hh + hl + lh) for ~fp32 accuracy.
// Epilogue: optional bias vector, fp32 accumulate, leaky; fp32 C or
// split-bf16 Oh/Ol (row-major, leading dim ldo).
// ---------------------------------------------------------------------------
template<bool AF32>
__global__ __launch_bounds__(512) void gemm_k(
    const float* __restrict__ Af, int ldaf,
    const __bf16* __restrict__ Ah, const __bf16* __restrict__ Al, int lda,
    const __bf16* __restrict__ BhT, const __bf16* __restrict__ BlT, int ldb,
    float* __restrict__ C, int ldc, const float* __restrict__ biasVec,
    __bf16* __restrict__ Oh, __bf16* __restrict__ Ol, int ldo,
    int M, int K, int accumulate, int leaky)
{
  __shared__ __bf16 Ash[8192];   // 256 rows x 32 k
  __shared__ __bf16 Asl[8192];
  __shared__ __bf16 Bsh[4096];   // 128 rows x 32 k
  __shared__ __bf16 Bsl[4096];

  const int tid  = threadIdx.x;
  const int lane = tid & 63;
  const int wid  = tid >> 6;     // 0..7
  const int wm   = wid & 3;      // 4 wave-rows of 64
  const int wn   = wid >> 2;     // 2 wave-cols of 64
  const int l15  = lane & 15;
  const int quad = lane >> 4;

  int mb, nb;
  swz_block(mb, nb);
  const int row0 = mb * 256;
  const int col0 = nb * 128;

  f32x4 acc[4][4] = {};
  const int nkt = K >> 5;

  // staging registers
  int4   avh0, avl0, avh1, avl1;        // !AF32 A (2 passes of 128 rows)
  int4   bvh, bvl;                      // B (1 pass)
  float4 ar0, ar1, ar2, ar3;            // AF32 A (4 passes of 64 rows)

  const int rr = tid >> 2;              // 0..127
  const int qq = tid & 3;

  auto loadB = [&](int kt) {
    const int kb = kt << 5;
    const size_t s = (size_t)(col0 + rr) * ldb + kb + qq * 8;
    bvh = *(const int4*)(BhT + s);
    bvl = *(const int4*)(BlT + s);
  };
  auto writeB = [&]() {
    const int o = rr * 32 + ((qq ^ ((rr >> 1) & 3)) << 3);
    *(int4*)&Bsh[o] = bvh;
    *(int4*)&Bsl[o] = bvl;
  };
  auto loadA16 = [&](int kt) {
    const int kb = kt << 5;
    int r0 = row0 + rr;       r0 = r0 < M ? r0 : M - 1;
    int r1 = row0 + rr + 128; r1 = r1 < M ? r1 : M - 1;
    const size_t s0 = (size_t)r0 * lda + kb + qq * 8;
    const size_t s1 = (size_t)r1 * lda + kb + qq * 8;
    avh0 = *(const int4*)(Ah + s0);
    avl0 = *(const int4*)(Al + s0);
    avh1 = *(const int4*)(Ah + s1);
    avl1 = *(const int4*)(Al + s1);
  };
  auto writeA16 = [&]() {
    const int m1 = rr + 128;
    const int o0 = rr * 32 + ((qq ^ ((rr >> 1) & 3)) << 3);
    const int o1 = m1 * 32 + ((qq ^ ((m1 >> 1) & 3)) << 3);
    *(int4*)&Ash[o0] = avh0;
    *(int4*)&Asl[o0] = avl0;
    *(int4*)&Ash[o1] = avh1;
    *(int4*)&Asl[o1] = avl1;
  };
  auto loadA32 = [&](int kt) {
    const int kb = (kt << 5) + (tid & 7) * 4;
    const int m  = tid >> 3;   // 0..63
    int r;
    r = row0 + m;       r = r < M ? r : M - 1; ar0 = *(const float4*)(Af + (size_t)r * ldaf + kb);
    r = row0 + m + 64;  r = r < M ? r : M - 1; ar1 = *(const float4*)(Af + (size_t)r * ldaf + kb);
    r = row0 + m + 128; r = r < M ? r : M - 1; ar2 = *(const float4*)(Af + (size_t)r * ldaf + kb);
    r = row0 + m + 192; r = r < M ? r : M - 1; ar3 = *(const float4*)(Af + (size_t)r * ldaf + kb);
  };
  auto writeA32 = [&]() {
    const int q16 = (tid & 7) >> 1;
    const int sub = (tid & 1) * 4;
    const int m0  = tid >> 3;
    const float4 regs[4] = {ar0, ar1, ar2, ar3};
    #pragma unroll
    for (int p = 0; p < 4; ++p) {
      const int m = m0 + p * 64;
      const float f[4] = {regs[p].x, regs[p].y, regs[p].z, regs[p].w};
      union { __bf16 b[4]; short4 s; } hh, ll;
      #pragma unroll
      for (int i = 0; i < 4; ++i) {
        const __bf16 hb = (__bf16)f[i];
        hh.b[i] = hb;
        ll.b[i] = (__bf16)(f[i] - (float)hb);
      }
      const int off = m * 32 + ((q16 ^ ((m >> 1) & 3)) << 3) + sub;
      *(short4*)&Ash[off] = hh.s;
      *(short4*)&Asl[off] = ll.s;
    }
  };

  // ---- prologue: tile 0 into LDS ------------------------------------------
  if constexpr (AF32) { loadA32(0); } else { loadA16(0); }
  loadB(0);
  if constexpr (AF32) { writeA32(); } else { writeA16(); }
  writeB();
  __syncthreads();

  // ---- main loop: frags+MFMA(cur) with loads(kt+1) in flight --------------
  for (int kt = 0; kt < nkt; ++kt) {
    bf16x8 fah[4], fal[4], fbh[4], fbl[4];
    #pragma unroll
    for (int t = 0; t < 4; ++t) {
      const int ar = wm * 64 + t * 16 + l15;
      const int br = wn * 64 + t * 16 + l15;
      const int as = ar * 32 + ((quad ^ ((ar >> 1) & 3)) << 3);
      const int bs = br * 32 + ((quad ^ ((br >> 1) & 3)) << 3);
      fah[t] = *(const bf16x8*)&Ash[as];
      fal[t] = *(const bf16x8*)&Asl[as];
      fbh[t] = *(const bf16x8*)&Bsh[bs];
      fbl[t] = *(const bf16x8*)&Bsl[bs];
    }

    const bool more = (kt + 1) < nkt;
    if (more) {
      if constexpr (AF32) { loadA32(kt + 1); } else { loadA16(kt + 1); }
      loadB(kt + 1);
    }

    #pragma unroll
    for (int mt = 0; mt < 4; ++mt)
      #pragma unroll
      for (int nt = 0; nt < 4; ++nt) {
        acc[mt][nt] = __builtin_amdgcn_mfma_f32_16x16x32_bf16(fah[mt], fbh[nt], acc[mt][nt], 0, 0, 0);
        acc[mt][nt] = __builtin_amdgcn_mfma_f32_16x16x32_bf16(fah[mt], fbl[nt], acc[mt][nt], 0, 0, 0);
        acc[mt][nt] = __builtin_amdgcn_mfma_f32_16x16x32_bf16(fal[mt], fbh[nt], acc[mt][nt], 0, 0, 0);
      }

    __syncthreads();            // all waves done reading; loads have landed
    if (more) {
      if constexpr (AF32) { writeA32(); } else { writeA16(); }
      writeB();
    }
    __syncthreads();            // next tile visible
  }

  // ---- epilogue: C/D layout col=lane&15, row=quad*4+reg --------------------
  #pragma unroll
  for (int mt = 0; mt < 4; ++mt)
    #pragma unroll
    for (int nt = 0; nt < 4; ++nt) {
      const int col = col0 + wn * 64 + nt * 16 + l15;
      const float bv = biasVec ? biasVec[col] : 0.0f;
      #pragma unroll
      for (int r = 0; r < 4; ++r) {
        const int row = row0 + wm * 64 + mt * 16 + quad * 4 + r;
        if (row < M) {
          float v = acc[mt][nt][r] + bv;
          if (accumulate) v += C[(size_t)row * ldc + col];
          if (leaky) v = leaky_f(v);
          if (Oh) {
            const __bf16 hv = (__bf16)v;
            Oh[(size_t)row * ldo + col] = hv;
            Ol[(size_t)row * ldo + col] = (__bf16)(v - (float)hv);
          } else {
            C[(size_t)row * ldc + col] = v;
          }
        }
      }
    }
}

// ---------------------------------------------------------------------------
// Weight prep: transpose + hi/lo split.  B:[Z][Kd][Nd] -> out:[Z][Nd][Kd]
// ---------------------------------------------------------------------------
__global__ void splitT_kernel(const float* __restrict__ B, __bf16* __restrict__ h,
                              __bf16* __restrict__ l, int Kd, int Nd, int total)
{
  int i = blockIdx.x * 256 + threadIdx.x;
  if (i >= total) return;
  int z   = i / (Kd * Nd);
  int rem = i - z * (Kd * Nd);
  int k = rem / Nd;
  int n = rem - k * Nd;
  float v = B[i];
  __bf16 hv = (__bf16)v;
  long o = (long)z * Kd * Nd + (long)n * Kd + k;
  h[o] = hv;
  l[o] = (__bf16)(v - (float)hv);
}

// Bcat stacked, generation-major with [WB-block | R-block] halves per gen:
// out layout [n][2048]; generation g owns kidx in [g*KTOT, (g+1)*KTOT).
// Within a generation (k local): k < KTOT/2: WB section, j = k>>8, d = g*DPG+j
//   -> invW[d*H + (k&255)][n]
// k >= KTOT/2: R section, j = (k-half)>>8, d = g*DPG+j
//   -> 0.5 * sum_b att[d*4+b] * invW[b*H + (k&255)][n]
// ---------------------------------------------------------------------------
__global__ void bcat_kernel(const float* __restrict__ invW, const float* __restrict__ att,
                            __bf16* __restrict__ h, __bf16* __restrict__ l, int DPG)
{
  int i = blockIdx.x * 256 + threadIdx.x;           // over 512 * 2048
  if (i >= OUT_F * NDIM * 512) return;
  const int n    = i >> 11;
  const int kidx = i & 2047;
  const int KTOT = DPG << 9;
  const int g    = kidx / KTOT;
  const int k    = kidx - g * KTOT;
  const int half = KTOT >> 1;
  float v;
  if (k < half) {
    const int d  = g * DPG + (k >> 8);
    const int kk = k & 255;
    v = invW[(long)(d * H_F + kk) * OUT_F + n];
  } else {
    const int k2 = k - half;
    const int d  = g * DPG + (k2 >> 8);
    const int kk = k2 & 255;
    float s = 0.f;
    #pragma unroll
    for (int b = 0; b < 4; ++b)
      s += att[d * 4 + b] * invW[(long)(b * H_F + kk) * OUT_F + n];
    v = 0.5f * s;
  }
  const __bf16 hv = (__bf16)v;
  const long o = (long)n * (NDIM * 512) + kidx;
  h[o] = hv;
  l[o] = (__bf16)(v - (float)hv);
}

// ---------------------------------------------------------------------------
// CSR build
// ---------------------------------------------------------------------------
__global__ void deg_count_kernel(const int* __restrict__ edges, int* __restrict__ cnt, int E)
{
  int i = blockIdx.x * 256 + threadIdx.x;
  if (i >= NDIM * E) return;
  int d = i / E;
  int e = i - d * E;
  int t = edges[(long)d * 2 * E + E + e];
  atomicAdd(&cnt[d * N_NODES + t], 1);
}

__global__ __launch_bounds__(1024) void scan_kernel(const int* __restrict__ cnt,
                                                    int* __restrict__ row_start,
                                                    float* __restrict__ dinv)
{
  const int d    = blockIdx.x;
  const int tid  = threadIdx.x;
  const int lane = tid & 63;
  const int wid  = tid >> 6;
  __shared__ int wsum[16];
  __shared__ int carry_s;
  if (tid == 0) carry_s = 0;
  __syncthreads();
  for (int base = 0; base < N_NODES; base += 1024) {
    int i = base + tid;
    int v = (i < N_NODES) ? cnt[d * N_NODES + i] : 0;
    if (i < N_NODES) dinv[d * N_NODES + i] = sqrtf(0.5f / (float)(v + 1));
    int incl = v;
    #pragma unroll
    for (int off = 1; off < 64; off <<= 1) {
      int nb = __shfl_up(incl, off, 64);
      if (lane >= off) incl += nb;
    }
    if (lane == 63) wsum[wid] = incl;
    __syncthreads();
    if (wid == 0 && lane < 16) {
      int s = wsum[lane];
      #pragma unroll
      for (int off = 1; off < 16; off <<= 1) {
        int nb = __shfl_up(s, off, 16);
        if (lane >= off) s += nb;
      }
      wsum[lane] = s;
    }
    __syncthreads();
    int waveoff = (wid == 0) ? 0 : wsum[wid - 1];
    if (i < N_NODES) row_start[d * (N_NODES + 1) + i] = carry_s + waveoff + incl - v;
    __syncthreads();
    if (tid == 1023) carry_s += wsum[15];
    __syncthreads();
  }
  if (tid == 0) row_start[d * (N_NODES + 1) + N_NODES] = carry_s;
}

__global__ void fill_kernel(const int* __restrict__ edges, const int* __restrict__ row_start,
                            int* __restrict__ fill_cnt, int* __restrict__ csr_src, int E)
{
  int i = blockIdx.x * 256 + threadIdx.x;
  if (i >= NDIM * E) return;
  int d = i / E;
  int e = i - d * E;
  int s = edges[(long)d * 2 * E + e];
  int t = edges[(long)d * 2 * E + E + e];
  int pos = row_start[d * (N_NODES + 1) + t] + atomicAdd(&fill_cnt[d * N_NODES + t], 1);
  csr_src[(long)d * E + pos] = s;
}

// ---------------------------------------------------------------------------
// Gather: one wave per dst node, 4-edge unroll (r5/r6-proven); writes WB split
// bf16 into the fat slot (row-major, leading dim ldw).
// ---------------------------------------------------------------------------
__global__ __launch_bounds__(256) void gather_aggr_kernel(
    const float* __restrict__ hw, const int* __restrict__ csr_src,
    const int* __restrict__ row_start, const float* __restrict__ dinv,
    const float* __restrict__ bias, __bf16* __restrict__ Wh, __bf16* __restrict__ Wl,
    int ldw)
{
  const int n = blockIdx.x * 4 + (threadIdx.x >> 6);
  const int lane = threadIdx.x & 63;
  const float dt = dinv[n];
  const float sl = dt * dt;
  const float4 b = *(const float4*)(bias + lane * 4);
  const float4 h = *(const float4*)(hw + (size_t)n * H_F + lane * 4);
  float4 a0 = make_float4(0.5f * b.x + sl * h.x, 0.5f * b.y + sl * h.y,
                          0.5f * b.z + sl * h.z, 0.5f * b.w + sl * h.w);
  float4 a1 = make_float4(0.f, 0.f, 0.f, 0.f);
  float4 a2 = make_float4(0.f, 0.f, 0.f, 0.f);
  float4 a3 = make_float4(0.f, 0.f, 0.f, 0.f);
  const int beg = row_start[n];
  const int end = row_start[n + 1];
  int j = beg;
  for (; j + 4 <= end; j += 4) {
    const int s0 = csr_src[j];
    const int s1 = csr_src[j + 1];
    const int s2 = csr_src[j + 2];
    const int s3 = csr_src[j + 3];
    const float nm0 = dt * dinv[s0];
    const float nm1 = dt * dinv[s1];
    const float nm2 = dt * dinv[s2];
    const float nm3 = dt * dinv[s3];
    const float4 v0 = *(const float4*)(hw + (size_t)s0 * H_F + lane * 4);
    const float4 v1 = *(const float4*)(hw + (size_t)s1 * H_F + lane * 4);
    const float4 v2 = *(const float4*)(hw + (size_t)s2 * H_F + lane * 4);
    const float4 v3 = *(const float4*)(hw + (size_t)s3 * H_F + lane * 4);
    a0.x = fmaf(nm0, v0.x, a0.x); a0.y = fmaf(nm0, v0.y, a0.y);
    a0.z = fmaf(nm0, v0.z, a0.z); a0.w = fmaf(nm0, v0.w, a0.w);
    a1.x = fmaf(nm1, v1.x, a1.x); a1.y = fmaf(nm1, v1.y, a1.y);
    a1.z = fmaf(nm1, v1.z, a1.z); a1.w = fmaf(nm1, v1.w, a1.w);
    a2.x = fmaf(nm2, v2.x, a2.x); a2.y = fmaf(nm2, v2.y, a2.y);
    a2.z = fmaf(nm2, v2.z, a2.z); a2.w = fmaf(nm2, v2.w, a2.w);
    a3.x = fmaf(nm3, v3.x, a3.x); a3.y = fmaf(nm3, v3.y, a3.y);
    a3.z = fmaf(nm3, v3.z, a3.z); a3.w = fmaf(nm3, v3.w, a3.w);
  }
  for (; j < end; ++j) {
    const int s0 = csr_src[j];
    const float nm0 = dt * dinv[s0];
    const float4 v0 = *(const float4*)(hw + (size_t)s0 * H_F + lane * 4);
    a0.x = fmaf(nm0, v0.x, a0.x); a0.y = fmaf(nm0, v0.y, a0.y);
    a0.z = fmaf(nm0, v0.z, a0.z); a0.w = fmaf(nm0, v0.w, a0.w);
  }
  const float av[4] = {a0.x + a1.x + a2.x + a3.x, a0.y + a1.y + a2.y + a3.y,
                       a0.z + a1.z + a2.z + a3.z, a0.w + a1.w + a2.w + a3.w};
  union { __bf16 b[4]; short4 s; } H, L;
  #pragma unroll
  for (int i = 0; i < 4; ++i) {
    const __bf16 hv = (__bf16)av[i];
    H.b[i] = hv;
    L.b[i] = (__bf16)(av[i] - (float)hv);
  }
  *(short4*)(Wh + (size_t)n * ldw + lane * 4) = H.s;
  *(short4*)(Wl + (size_t)n * ldw + lane * 4) = L.s;
}

// ---------------------------------------------------------------------------
// Attention small kernels
// ---------------------------------------------------------------------------
__global__ void att_dot_kernel(const float* __restrict__ T, const float* __restrict__ P,
                               float* __restrict__ out16)
{
  const int a = blockIdx.x >> 2;
  const int b = blockIdx.x & 3;
  const float* ta = T + (long)a * (IN_F * H_F);
  const float* pb = P + (long)b * (IN_F * H_F);
  float s = 0.f;
  for (int i = threadIdx.x; i < IN_F * H_F; i += 256) s += ta[i] * pb[i];
  #pragma unroll
  for (int off = 32; off > 0; off >>= 1) s += __shfl_down(s, off, 64);
  __shared__ float red[4];
  if ((threadIdx.x & 63) == 0) red[threadIdx.x >> 6] = s;
  __syncthreads();
  if (threadIdx.x == 0) out16[blockIdx.x] = red[0] + red[1] + red[2] + red[3];
}

__global__ void att_softmax_kernel(const float* __restrict__ raw, float* __restrict__ att)
{
  int b = threadIdx.x;
  if (b < 4) {
    float r0 = raw[b], r1 = raw[4 + b], r2 = raw[8 + b], r3 = raw[12 + b];
    float m = fmaxf(fmaxf(r0, r1), fmaxf(r2, r3));
    float e0 = expf(r0 - m), e1 = expf(r1 - m), e2 = expf(r2 - m), e3 = expf(r3 - m);
    float inv = 1.0f / (e0 + e1 + e2 + e3);
    att[b] = e0 * inv; att[4 + b] = e1 * inv; att[8 + b] = e2 * inv; att[12 + b] = e3 * inv;
  }
}

// ---------------------------------------------------------------------------
extern "C" void kernel_launch(void* const* d_in, const int* in_sizes, int n_in,
                              void* d_out, int out_size, void* d_ws, size_t ws_size,
                              hipStream_t stream)
{
  const float* x     = (const float*)d_in[0];
  const int*   edges = (const int*)d_in[1];
  const float* proj  = (const float*)d_in[2];
  const float* gcnW  = (const float*)d_in[3];
  const float* gcnB  = (const float*)d_in[4];
  const float* bil   = (const float*)d_in[5];
  const float* invW  = (const float*)d_in[6];
  const float* invB  = (const float*)d_in[7];
  float* out = (float*)d_out;

  // ---- workspace: fixed part (~77 MB) ----
  float* HWB       = (float*)d_ws;                    // NH fp32 (gather input)
  float* dinv      = HWB + NH;                        // NDIM*N
  float* Tbuf      = dinv + NDIM * N_NODES;           // NDIM*IN_F*H_F
  float* att_raw   = Tbuf + (long)NDIM * IN_F * H_F;  // 16
  float* att       = att_raw + 16;                    // 16
  int*   cnt       = (int*)(att + 16);                // NDIM*N
  int*   fill_cnt  = cnt + NDIM * N_NODES;            // NDIM*N
  int*   row_start = fill_cnt + NDIM * N_NODES;       // NDIM*(N+1)
  int*   csr_src   = row_start + NDIM * (N_NODES + 1);// NDIM*E
  __bf16* projTh   = (__bf16*)(csr_src + (long)NDIM * N_EDGE);   // [4][256n][512k]
  __bf16* projTl   = projTh + (long)NDIM * IN_F * H_F;
  __bf16* gcnWTh   = projTl + (long)NDIM * IN_F * H_F;           // [4][256n][256k]
  __bf16* gcnWTl   = gcnWTh + (long)NDIM * H_F * H_F;
  __bf16* bcatTh   = gcnWTl + (long)NDIM * H_F * H_F;            // [512n][2048k]
  __bf16* bcatTl   = bcatTh + (long)NDIM * OUT_F * 512;
  __bf16* bilTh    = bcatTl + (long)NDIM * OUT_F * 512;          // [256n][256k]
  __bf16* bilTl    = bilTh + (long)H_F * H_F;
  __bf16* fatH     = bilTl + (long)H_F * H_F;

  // ---- merge tiers: fat = [WB-block | R-block] per generation,
  //      rows [N_NODES][KTOT] hi/lo ----
  const size_t base_bytes = (size_t)((char*)fatH - (char*)d_ws);
  auto fatBytes = [](int ktot) { return (size_t)2 * N_NODES * ktot * sizeof(__bf16); };
  int KTOT;
  if      (ws_size >= base_bytes + fatBytes(2048)) KTOT = 2048;
  else if (ws_size >= base_bytes + fatBytes(1024)) KTOT = 1024;
  else                                             KTOT = 512;
  const int DPG  = KTOT / 512;
  const int NGEN = NDIM / DPG;
  const int half = KTOT / 2;
  __bf16* fatL = fatH + (size_t)N_NODES * KTOT;

  const int MBL = (N_NODES + 255) / 256;              // 196

  // --- CSR build ---
  hipMemsetAsync(cnt, 0, (size_t)2 * NDIM * N_NODES * sizeof(int), stream);
  deg_count_kernel<<<(NDIM * N_EDGE + 255) / 256, 256, 0, stream>>>(edges, cnt, N_EDGE);
  scan_kernel<<<NDIM, 1024, 0, stream>>>(cnt, row_start, dinv);
  fill_kernel<<<(NDIM * N_EDGE + 255) / 256, 256, 0, stream>>>(edges, row_start, fill_cnt,
                                                               csr_src, N_EDGE);

  // --- weight prep (transpose + split) ---
  splitT_kernel<<<(NDIM * IN_F * H_F + 255) / 256, 256, 0, stream>>>(
      proj, projTh, projTl, IN_F, H_F, NDIM * IN_F * H_F);
  splitT_kernel<<<(NDIM * H_F * H_F + 255) / 256, 256, 0, stream>>>(
      gcnW, gcnWTh, gcnWTl, H_F, H_F, NDIM * H_F * H_F);
  splitT_kernel<<<(H_F * H_F + 255) / 256, 256, 0, stream>>>(
      bil, bilTh, bilTl, H_F, H_F, H_F * H_F);

  // --- attention: T_a = proj_a @ bil (AF32, M=512 -> 2 row-blocks) ---
  for (int a = 0; a < NDIM; ++a)
    gemm_k<true><<<dim3(H_F / 128, IN_F / 256), 512, 0, stream>>>(
        proj + (long)a * IN_F * H_F, H_F,
        nullptr, nullptr, 0,
        bilTh, bilTl, H_F,
        Tbuf + (long)a * IN_F * H_F, H_F, nullptr,
        nullptr, nullptr, 0,
        IN_F, H_F, 0, 0);
  att_dot_kernel<<<16, 256, 0, stream>>>(Tbuf, proj, att_raw);
  att_softmax_kernel<<<1, 64, 0, stream>>>(att_raw, att);
  bcat_kernel<<<(OUT_F * NDIM * 512 + 255) / 256, 256, 0, stream>>>(
      invW, att, bcatTh, bcatTl, DPG);

  // --- per-generation pipeline ---
  for (int g = 0; g < NGEN; ++g) {
    // G1 merged: R_{g*DPG..} = leaky(x @ [proj pair]) -> fat cols [half, KTOT)
    // B = projT rows for the DPG dims (contiguous), N = DPG*256.
    gemm_k<true><<<dim3(DPG * 256 / 128, MBL), 512, 0, stream>>>(
        x, IN_F,
        nullptr, nullptr, 0,
        projTh + (size_t)(g * DPG) * H_F * IN_F, projTl + (size_t)(g * DPG) * H_F * IN_F, IN_F,
        nullptr, 0, nullptr,
        fatH + half, fatL + half, KTOT,
        N_NODES, IN_F, 0, 1);

    for (int j = 0; j < DPG; ++j) {
      const int d = g * DPG + j;

      // G2: HWB = R_d @ gcnW[d] (fp32 out for gather); A = fat cols half+j*256
      gemm_k<false><<<dim3(H_F / 128, MBL), 512, 0, stream>>>(
          nullptr, 0,
          fatH + half + j * 256, fatL + half + j * 256, KTOT,
          gcnWTh + (long)d * H_F * H_F, gcnWTl + (long)d * H_F * H_F, H_F,
          HWB, H_F, nullptr,
          nullptr, nullptr, 0,
          N_NODES, H_F, 0, 0);

      // WB_d = 0.5*bias + selfloop + neighbor gather -> fat cols j*256
      gather_aggr_kernel<<<N_NODES / 4, 256, 0, stream>>>(
          HWB, csr_src + (long)d * N_EDGE, row_start + d * (N_NODES + 1),
          dinv + d * N_NODES, gcnB + d * H_F,
          fatH + j * 256, fatL + j * 256, KTOT);
    }

    // G3_g: out (+)= fat @ bcat[:, g*KTOT..]^T   (K=KTOT; g0 folds invB)
    gemm_k<false><<<dim3(OUT_F / 128, MBL), 512, 0, stream>>>(
        nullptr, 0,
        fatH, fatL, KTOT,
        bcatTh + (long)g * KTOT, bcatTl + (long)g * KTOT, NDIM * 512,
        out, OUT_F, (g == 0) ? invB : nullptr,
        nullptr, nullptr, 0,
        N_NODES, KTOT, (g == 0) ? 0 : 1, (g == NGEN - 1) ? 1 : 0);
  }

  (void)in_sizes; (void)n_in; (void)out_size;
}